// Round 7
// baseline (855.181 us; speedup 1.0000x reference)
//
#include <hip/hip_runtime.h>
#include <hip/hip_fp16.h>
#include <stdint.h>

// PrunedInt4Linear: y = x @ dequant(q, scales)^T + bias
// Round 7: LDS-traffic attack. B operand bypasses LDS: deq_w_pack writes B in
// MFMA-fragment order so each lane's global dwordx4 load IS its fragment
// (register-direct, L2-served). LDS = A-only 4x16KiB ring (64 KiB -> 2
// blocks/CU). One barrier per K-step (r6-proven publish-then-read order),
// counted vmcnt(10) for the mixed A-stage/B-load FIFO, fences pin vmem order.

#define M_DIM 8192
#define N_DIM 11008
#define K_DIM 4096
#define MT_TILES 32            // 8192 / 256
#define NT_TILES 43            // 11008 / 256
#define K_TILES 128            // 4096 / 32
#define SLAB 8192              // shorts per (tile, kt) slab: 256 rows * 32 k

typedef short short8 __attribute__((ext_vector_type(8)));   // 8 bf16
typedef float floatx4 __attribute__((ext_vector_type(4)));

// f32 -> bf16, round-to-nearest-even
__device__ __forceinline__ unsigned short f2bf(float f) {
  union { float f; uint32_t u; } c; c.f = f;
  uint32_t u = c.u;
  return (unsigned short)((u + 0x7FFFu + ((u >> 16) & 1u)) >> 16);
}

__device__ __forceinline__ float load_sc(const void* p, size_t idx, bool is_f32) {
  if (is_f32) return ((const float*)p)[idx];
  return __half2float(((const __half*)p)[idx]);
}

// ---- dtype sniffs (verified rounds 2-6) ----
__device__ __forceinline__ bool sniff_q_is_i32(const void* qv) {
  const int* w = (const int*)qv;
  bool ok = true;
  #pragma unroll
  for (int j = 0; j < 16; ++j) {
    int v = w[j];
    ok = ok && (v == (int)(signed char)(v & 0xFF));
  }
  return ok;
}
__device__ __forceinline__ bool sniff_s_is_f32(const void* sv) {
  const float* f = (const float*)sv;
  bool ok = true;
  #pragma unroll
  for (int j = 0; j < 8; ++j) {
    float v = f[j];
    ok = ok && (v > 4e-4f) && (v < 6e-2f);
  }
  return ok;
}

// async global -> LDS, 16B per lane (dest = wave-uniform base + lane*16)
__device__ __forceinline__ void gload_lds16(const short* g, short* l) {
  __builtin_amdgcn_global_load_lds(
      (const __attribute__((address_space(1))) uint32_t*)g,
      (__attribute__((address_space(3))) uint32_t*)l, 16, 0, 0);
}

// ============ prep: x f32 -> bf16, tile-packed + swizzled (r4/r6-verified) ==
// xh layout: [mt 32][kt 128][slab 8192 shorts]; element (r,k): slab short idx
//   r*32 + ((k/8) ^ ((r>>1)&3))*8 + (k%8)
__global__ __launch_bounds__(256)
void cvt_x_pack(const float* __restrict__ x, short* __restrict__ xh) {
  const int b = blockIdx.x;              // 32*256 = 8192 blocks
  const int mt = b >> 8;
  const int rem = b & 255;
  const int kt = rem >> 1, half = rem & 1;
  const int tid = threadIdx.x;
  const int r = half * 128 + (tid >> 1);
  const int s0 = (tid & 1) * 2;          // slot base (0 or 2)
  const int k0 = kt * 32 + s0 * 8;

  const float4* p = (const float4*)(x + (size_t)(mt * 256 + r) * K_DIM + k0);
  float4 f0 = p[0], f1 = p[1], f2 = p[2], f3 = p[3];
  short8 h0, h1;
  h0[0]=f2bf(f0.x); h0[1]=f2bf(f0.y); h0[2]=f2bf(f0.z); h0[3]=f2bf(f0.w);
  h0[4]=f2bf(f1.x); h0[5]=f2bf(f1.y); h0[6]=f2bf(f1.z); h0[7]=f2bf(f1.w);
  h1[0]=f2bf(f2.x); h1[1]=f2bf(f2.y); h1[2]=f2bf(f2.z); h1[3]=f2bf(f2.w);
  h1[4]=f2bf(f3.x); h1[5]=f2bf(f3.y); h1[6]=f2bf(f3.z); h1[7]=f2bf(f3.w);

  const int w = (r >> 1) & 3;
  short* slab = xh + ((size_t)mt * K_TILES + kt) * SLAB;
  *(short8*)&slab[r * 32 + ((s0    ) ^ w) * 8] = h0;
  *(short8*)&slab[r * 32 + ((s0 + 1) ^ w) * 8] = h1;
}

// ============ prep: W -> bf16 in MFMA-FRAGMENT order ============
// wq layout: [nt 43][kt 128][cb 16][lane 64][8 shorts]  (SLAB shorts per nt,kt)
//   cb = col-block (16 cols); lane = (col&15) + 16*kslot; 8 shorts = k kslot*8..+7
// A wave's B-fragment (cols cb*16+lr, k lk*8..+7) = contiguous 1 KiB at
// cb*512 + lane*8 -> one coalesced global_load_dwordx4 per lane.
__global__ __launch_bounds__(256)
void deq_w_pack(const void* __restrict__ qv, const void* __restrict__ sv,
                short* __restrict__ wq) {
  const bool q_is_i32 = sniff_q_is_i32(qv);
  const bool s_is_f32 = sniff_s_is_f32(sv);
  const int b = blockIdx.x;              // 43*256 = 11008 blocks
  const int nt = b >> 8;
  const int rem = b & 255;
  const int kt = rem >> 1, half = rem & 1;
  const int tid = threadIdx.x;
  const int r = half * 128 + (tid >> 1);   // col within tile [0,256)
  const int s0 = (tid & 1) * 2;            // k-slot base (0 or 2)
  const int o = nt * 256 + r;
  const int k0 = kt * 32 + s0 * 8;

  const float s = load_sc(sv, (size_t)o * 64 + (kt >> 1), s_is_f32);

  int codes[16];
  if (q_is_i32) {
    const int* qq = (const int*)qv + (size_t)o * K_DIM + k0;
    #pragma unroll
    for (int j = 0; j < 4; ++j) {
      int4 t = ((const int4*)qq)[j];
      codes[j*4+0]=t.x; codes[j*4+1]=t.y; codes[j*4+2]=t.z; codes[j*4+3]=t.w;
    }
  } else {
    union { int4 v; int8_t c[16]; } u;
    u.v = *(const int4*)((const int8_t*)qv + (size_t)o * K_DIM + k0);
    #pragma unroll
    for (int j = 0; j < 16; ++j) codes[j] = (int)u.c[j];
  }

  short8 h0, h1;
  #pragma unroll
  for (int j = 0; j < 8; ++j) h0[j] = f2bf((float)codes[j] * s);
  #pragma unroll
  for (int j = 0; j < 8; ++j) h1[j] = f2bf((float)codes[8 + j] * s);

  short* slab = wq + ((size_t)nt * K_TILES + kt) * SLAB;
  const int cb = r >> 4, lr = r & 15;
  *(short8*)&slab[cb * 512 + (lr + 16 * (s0    )) * 8] = h0;
  *(short8*)&slab[cb * 512 + (lr + 16 * (s0 + 1)) * 8] = h1;
}

// ============ GEMM: 256x256, BK=32, 8 waves; A via LDS ring, B reg-direct ===
__global__ __launch_bounds__(512)
void gemm8(const short* __restrict__ xh, const short* __restrict__ wq,
           const void* __restrict__ sv, const void* __restrict__ bv,
           float* __restrict__ C) {
  __shared__ __align__(16) short lds[4 * SLAB];   // 64 KiB: 4-deep A ring

  const bool s_is_f32 = sniff_s_is_f32(sv);   // bias dtype tracks scales

  const int tid  = threadIdx.x;
  const int lane = tid & 63;
  const int wid  = tid >> 6;                  // 8 waves
  const int wm = wid >> 2, wn = wid & 3;      // 2x4 -> 128x64 out per wave
  const int lr = lane & 15, lk = lane >> 4;

  // nt-major dispatch (r6-verified: FETCH 1.5G->0.55G)
  const int bid = blockIdx.x;
  const int xcd = bid & 7;
  const int seq = bid >> 3;                   // [0,172)
  const int nt  = seq >> 2;                   // [0,43)
  const int mt  = xcd * 4 + (seq & 3);        // [0,32)

  const short* Aslab = xh + (size_t)mt * K_TILES * SLAB;
  const short* Bslab = wq + (size_t)nt * K_TILES * SLAB;

  // A-fragment LDS offsets (r4/r6-verified, 0 conflicts)
  const int swz8 = (lk ^ ((lr >> 1) & 3)) << 3;
  int aoff[8];
  #pragma unroll
  for (int mi = 0; mi < 8; ++mi) aoff[mi] = (wm * 128 + mi * 16 + lr) * 32 + swz8;
  // B fragment base (shorts): frag ni at boff + ni*512
  const int boff = (wn * 4) * 512 + lane * 8;

  floatx4 acc[8][4];
  #pragma unroll
  for (int i = 0; i < 8; ++i)
    #pragma unroll
    for (int j = 0; j < 4; ++j)
      acc[i][j] = (floatx4){0.f, 0.f, 0.f, 0.f};

  short8 fa[8], ga[8], be[4], bo[4];   // named sets (rule #20)

#define FENCE asm volatile("" ::: "memory")
#define VMCNT(n) asm volatile("s_waitcnt vmcnt(" #n ")" ::: "memory")
#define BARRIER do { FENCE; __builtin_amdgcn_s_barrier(); FENCE; } while (0)

#define STAGE_A(t) do {                                                 \
    const short* gA_ = Aslab + (size_t)(t) * SLAB;                      \
    short* lA_ = &lds[((t) & 3) * SLAB];                                \
    gload_lds16(gA_ + tid * 8,        lA_ + tid * 8);                   \
    gload_lds16(gA_ + 4096 + tid * 8, lA_ + 4096 + tid * 8);            \
    FENCE;                                                              \
  } while (0)

#define LOADB(db, t) do {                                               \
    const short* gB_ = Bslab + (size_t)(t) * SLAB + boff;               \
    _Pragma("unroll")                                                   \
    for (int ni = 0; ni < 4; ++ni) db[ni] = *(const short8*)(gB_ + ni * 512); \
    FENCE;                                                              \
  } while (0)

#define LOADF_A(da, t) do {                                             \
    const short* lA_ = &lds[((t) & 3) * SLAB];                          \
    _Pragma("unroll")                                                   \
    for (int mi = 0; mi < 8; ++mi) da[mi] = *(const short8*)&lA_[aoff[mi]]; \
  } while (0)

#define DOMFMA(sa, sb) do {                                             \
    __builtin_amdgcn_s_setprio(1);                                      \
    _Pragma("unroll")                                                   \
    for (int mi = 0; mi < 8; ++mi)                                      \
      _Pragma("unroll")                                                 \
      for (int ni = 0; ni < 4; ++ni)                                    \
        acc[mi][ni] = __builtin_amdgcn_mfma_f32_16x16x32_bf16(          \
            sa[mi], sb[ni], acc[mi][ni], 0, 0, 0);                      \
    __builtin_amdgcn_s_setprio(0);                                      \
  } while (0)

  // prologue -- vmem FIFO: A0(2) A1(2) B0(4) A2(2) B1(4)
  STAGE_A(0);
  STAGE_A(1);
  LOADB(be, 0);
  STAGE_A(2);
  LOADB(bo, 1);
  VMCNT(12);                   // retire A0 (12 younger remain)
  BARRIER;                     // A0 published
  LOADF_A(fa, 0);

  // Steady state: at top of half-iter t the FIFO is
  //   [A(t+1)(2), B(t)(4), A(t+2)(2), B(t+1)(4)] = 12
  // VMCNT(10) retires exactly A(t+1); BARRIER publishes it (r6 order:
  // publish-then-read). STAGE_A(t+3) overwrites ring slot (t-1)&3, whose
  // reads were lgkm-retired before each wave's barrier arrival. B(t) is
  // waited by the compiler's own vmcnt before DOMFMA.
  for (int kt = 0; kt < 124; kt += 2) {
    VMCNT(10);
    BARRIER;
    STAGE_A(kt + 3);
    LOADF_A(ga, kt + 1);
    DOMFMA(fa, be);            // tile kt
    LOADB(be, kt + 2);
    VMCNT(10);
    BARRIER;
    STAGE_A(kt + 4);
    LOADF_A(fa, kt + 2);
    DOMFMA(ga, bo);            // tile kt+1
    LOADB(bo, kt + 3);
  }

  // tail: fa=frags(124), be=B(124), bo=B(125); staged through A(126)
  VMCNT(10);                   // retire A(125)
  BARRIER;
  STAGE_A(127);
  LOADF_A(ga, 125);
  DOMFMA(fa, be);              // 124
  LOADB(be, 126);
  VMCNT(10);                   // retire A(126)
  BARRIER;
  LOADF_A(fa, 126);
  DOMFMA(ga, bo);              // 125
  LOADB(bo, 127);
  VMCNT(8);                    // retire A(127)  [B126(4)+B127(4) younger]
  BARRIER;
  LOADF_A(ga, 127);
  DOMFMA(fa, be);              // 126
  DOMFMA(ga, bo);              // 127

#undef STAGE_A
#undef LOADB
#undef LOADF_A
#undef DOMFMA
#undef FENCE
#undef VMCNT
#undef BARRIER

  // epilogue: C/D layout col = lane&15, row = (lane>>4)*4 + reg (verified)
  #pragma unroll
  for (int ni = 0; ni < 4; ++ni) {
    const int col = nt * 256 + wn * 64 + ni * 16 + lr;
    const float bvf = load_sc(bv, (size_t)col, s_is_f32);
    #pragma unroll
    for (int mi = 0; mi < 8; ++mi) {
      const int rbase = mt * 256 + wm * 128 + mi * 16 + lk * 4;
      #pragma unroll
      for (int rr = 0; rr < 4; ++rr)
        C[(size_t)(rbase + rr) * N_DIM + col] = acc[mi][ni][rr] + bvf;
    }
  }
}

// ============ fallback: round-2-verified fully fused kernel ============
__global__ __launch_bounds__(256)
void gemm_fused(const float* __restrict__ x, const void* __restrict__ qv,
                const void* __restrict__ sv, const void* __restrict__ bv,
                float* __restrict__ C) {
  __shared__ __align__(16) short As[128 * 64];
  __shared__ __align__(16) short Bs[128 * 64];

  const bool q_is_i32 = sniff_q_is_i32(qv);
  const bool s_is_f32 = sniff_s_is_f32(sv);

  const int tid  = threadIdx.x;
  const int lane = tid & 63;
  const int wid  = tid >> 6;
  const int wm = wid >> 1, wn = wid & 1;
  const int lr = lane & 15, lk = lane >> 4;

  const int nwg = gridDim.x;
  const int cpx = nwg >> 3;
  const int bid = blockIdx.x;
  const int swz = (bid & 7) * cpx + (bid >> 3);
  const int per_g = 4 * 86;
  const int g = swz / per_g;
  const int r = swz - g * per_g;
  const int mt = (g << 2) + (r & 3);
  const int nt = r >> 2;

  const int row0 = mt * 128;
  const int col0 = nt * 128;

  floatx4 acc[4][4];
  #pragma unroll
  for (int i = 0; i < 4; ++i)
    #pragma unroll
    for (int j = 0; j < 4; ++j)
      acc[i][j] = (floatx4){0.f, 0.f, 0.f, 0.f};

  for (int kt = 0; kt < K_DIM / 64; ++kt) {
    const int k0 = kt * 64;
    #pragma unroll
    for (int i = 0; i < 4; ++i) {
      const int cid = i * 256 + tid;
      const int arow = cid >> 3, ac = (cid & 7) << 3;
      const float4* p = (const float4*)(x + (size_t)(row0 + arow) * K_DIM + k0 + ac);
      float4 a = p[0], b = p[1];
      short8 h;
      h[0]=f2bf(a.x); h[1]=f2bf(a.y); h[2]=f2bf(a.z); h[3]=f2bf(a.w);
      h[4]=f2bf(b.x); h[5]=f2bf(b.y); h[6]=f2bf(b.z); h[7]=f2bf(b.w);
      *(short8*)&As[arow * 64 + ac] = h;
    }
    #pragma unroll
    for (int i = 0; i < 2; ++i) {
      const int cid = i * 256 + tid;
      const int brow = cid >> 2, bc = (cid & 3) << 4;
      const float s = load_sc(sv, (size_t)(col0 + brow) * 64 + kt, s_is_f32);
      int codes[16];
      if (q_is_i32) {
        const int* qq = (const int*)qv + (size_t)(col0 + brow) * K_DIM + k0 + bc;
        #pragma unroll
        for (int j = 0; j < 4; ++j) {
          int4 t = ((const int4*)qq)[j];
          codes[j*4+0]=t.x; codes[j*4+1]=t.y; codes[j*4+2]=t.z; codes[j*4+3]=t.w;
        }
      } else {
        union { int4 v; int8_t c[16]; } u;
        u.v = *(const int4*)((const int8_t*)qv + (size_t)(col0 + brow) * K_DIM + k0 + bc);
        #pragma unroll
        for (int j = 0; j < 16; ++j) codes[j] = (int)u.c[j];
      }
      short8 h0, h1;
      #pragma unroll
      for (int j = 0; j < 8; ++j) h0[j] = f2bf((float)codes[j] * s);
      #pragma unroll
      for (int j = 0; j < 8; ++j) h1[j] = f2bf((float)codes[8 + j] * s);
      *(short8*)&Bs[brow * 64 + bc]     = h0;
      *(short8*)&Bs[brow * 64 + bc + 8] = h1;
    }
    __syncthreads();
    #pragma unroll
    for (int ks = 0; ks < 2; ++ks) {
      short8 a[4], b[4];
      #pragma unroll
      for (int mi = 0; mi < 4; ++mi)
        a[mi] = *(const short8*)&As[(wm * 64 + mi * 16 + lr) * 64 + ks * 32 + lk * 8];
      #pragma unroll
      for (int ni = 0; ni < 4; ++ni)
        b[ni] = *(const short8*)&Bs[(wn * 64 + ni * 16 + lr) * 64 + ks * 32 + lk * 8];
      #pragma unroll
      for (int mi = 0; mi < 4; ++mi)
        #pragma unroll
        for (int ni = 0; ni < 4; ++ni)
          acc[mi][ni] = __builtin_amdgcn_mfma_f32_16x16x32_bf16(
              a[mi], b[ni], acc[mi][ni], 0, 0, 0);
    }
    __syncthreads();
  }

  #pragma unroll
  for (int ni = 0; ni < 4; ++ni) {
    const int col = col0 + wn * 64 + ni * 16 + lr;
    const float bvf = load_sc(bv, (size_t)col, s_is_f32);
    #pragma unroll
    for (int mi = 0; mi < 4; ++mi) {
      const int rbase = row0 + wm * 64 + mi * 16 + lk * 4;
      #pragma unroll
      for (int rr = 0; rr < 4; ++rr)
        C[(size_t)(rbase + rr) * N_DIM + col] = acc[mi][ni][rr] + bvf;
    }
  }
}

extern "C" void kernel_launch(void* const* d_in, const int* in_sizes, int n_in,
                              void* d_out, int out_size, void* d_ws, size_t ws_size,
                              hipStream_t stream) {
  const float* x  = (const float*)d_in[0];
  const void*  q  = (const void*)d_in[1];
  const void*  sc = (const void*)d_in[2];
  const void*  bs = (const void*)d_in[3];
  float* y = (float*)d_out;
  (void)in_sizes; (void)n_in; (void)out_size;

  const size_t xh_bytes = (size_t)M_DIM * K_DIM * 2;   // 64 MiB
  const size_t wq_bytes = (size_t)N_DIM * K_DIM * 2;   // ~86 MiB

  if (ws_size >= xh_bytes + wq_bytes) {   // confirmed available (r3-r6)
    short* xh = (short*)d_ws;
    short* wq = (short*)((char*)d_ws + xh_bytes);
    cvt_x_pack<<<MT_TILES * 256, dim3(256), 0, stream>>>(x, xh);
    deq_w_pack<<<NT_TILES * 256, dim3(256), 0, stream>>>(q, sc, wq);
    gemm8<<<MT_TILES * NT_TILES, dim3(512), 0, stream>>>(xh, wq, sc, bs, y);
  } else {
    gemm_fused<<<(M_DIM / 128) * (N_DIM / 128), dim3(256), 0, stream>>>(x, q, sc, bs, y);
  }
}

// Round 8
// 759.706 us; speedup vs baseline: 1.1257x; 1.1257x over previous
//
#include <hip/hip_runtime.h>
#include <hip/hip_fp16.h>
#include <stdint.h>

// PrunedInt4Linear: y = x @ dequant(q, scales)^T + bias
// Round 8: GEMM = r6 verbatim (proven 690 us, 1.07 PF). Prep kernels fused
// into ONE dispatch (W-dequant blocks + x-convert blocks run concurrently).
// r7 lesson: occupancy is register-pinned (256 regs/wave -> 8 waves/CU);
// B stays in LDS where MFMA deps are compiler-visible lgkm.

#define M_DIM 8192
#define N_DIM 11008
#define K_DIM 4096
#define MT_TILES 32            // 8192 / 256
#define NT_TILES 43            // 11008 / 256
#define K_TILES 128            // 4096 / 32
#define SLAB 8192              // shorts per (tile, kt) slab: 256 rows * 32 k

typedef short short8 __attribute__((ext_vector_type(8)));   // 8 bf16
typedef float floatx4 __attribute__((ext_vector_type(4)));

// f32 -> bf16, round-to-nearest-even
__device__ __forceinline__ unsigned short f2bf(float f) {
  union { float f; uint32_t u; } c; c.f = f;
  uint32_t u = c.u;
  return (unsigned short)((u + 0x7FFFu + ((u >> 16) & 1u)) >> 16);
}

__device__ __forceinline__ float load_sc(const void* p, size_t idx, bool is_f32) {
  if (is_f32) return ((const float*)p)[idx];
  return __half2float(((const __half*)p)[idx]);
}

// ---- dtype sniffs (verified rounds 2-7) ----
__device__ __forceinline__ bool sniff_q_is_i32(const void* qv) {
  const int* w = (const int*)qv;
  bool ok = true;
  #pragma unroll
  for (int j = 0; j < 16; ++j) {
    int v = w[j];
    ok = ok && (v == (int)(signed char)(v & 0xFF));
  }
  return ok;
}
__device__ __forceinline__ bool sniff_s_is_f32(const void* sv) {
  const float* f = (const float*)sv;
  bool ok = true;
  #pragma unroll
  for (int j = 0; j < 8; ++j) {
    float v = f[j];
    ok = ok && (v > 4e-4f) && (v < 6e-2f);
  }
  return ok;
}

// async global -> LDS, 16B per lane (dest = wave-uniform base + lane*16)
__device__ __forceinline__ void gload_lds16(const short* g, short* l) {
  __builtin_amdgcn_global_load_lds(
      (const __attribute__((address_space(1))) uint32_t*)g,
      (__attribute__((address_space(3))) uint32_t*)l, 16, 0, 0);
}

// ============ fused prep: blocks [0, NT_TILES*256) dequant W;
//              blocks [NT_TILES*256, +MT_TILES*256) convert x ============
// layouts identical to r4/r6-verified pack kernels:
// xh: [mt 32][kt 128][slab]; (r,k) at r*32 + ((k/8) ^ ((r>>1)&3))*8 + (k%8)
// wq: [nt 43][kt 128][slab]; same within-slab swizzle (cols as rows)
__global__ __launch_bounds__(256)
void prep_fused(const float* __restrict__ x, const void* __restrict__ qv,
                const void* __restrict__ sv,
                short* __restrict__ xh, short* __restrict__ wq) {
  const int tid = threadIdx.x;
  int b = blockIdx.x;

  if (b < NT_TILES * 256) {
    // ---- W dequant (r6 deq_w_pack body) ----
    const bool q_is_i32 = sniff_q_is_i32(qv);
    const bool s_is_f32 = sniff_s_is_f32(sv);
    const int nt = b >> 8;
    const int rem = b & 255;
    const int kt = rem >> 1, half = rem & 1;
    const int r = half * 128 + (tid >> 1);
    const int s0 = (tid & 1) * 2;
    const int o = nt * 256 + r;
    const int k0 = kt * 32 + s0 * 8;

    const float s = load_sc(sv, (size_t)o * 64 + (kt >> 1), s_is_f32);

    int codes[16];
    if (q_is_i32) {
      const int* qq = (const int*)qv + (size_t)o * K_DIM + k0;
      #pragma unroll
      for (int j = 0; j < 4; ++j) {
        int4 t = ((const int4*)qq)[j];
        codes[j*4+0]=t.x; codes[j*4+1]=t.y; codes[j*4+2]=t.z; codes[j*4+3]=t.w;
      }
    } else {
      union { int4 v; int8_t c[16]; } u;
      u.v = *(const int4*)((const int8_t*)qv + (size_t)o * K_DIM + k0);
      #pragma unroll
      for (int j = 0; j < 16; ++j) codes[j] = (int)u.c[j];
    }

    short8 h0, h1;
    #pragma unroll
    for (int j = 0; j < 8; ++j) h0[j] = f2bf((float)codes[j] * s);
    #pragma unroll
    for (int j = 0; j < 8; ++j) h1[j] = f2bf((float)codes[8 + j] * s);

    const int w = (r >> 1) & 3;
    short* slab = wq + ((size_t)nt * K_TILES + kt) * SLAB;
    *(short8*)&slab[r * 32 + ((s0    ) ^ w) * 8] = h0;
    *(short8*)&slab[r * 32 + ((s0 + 1) ^ w) * 8] = h1;
  } else {
    // ---- x convert (r6 cvt_x_pack body) ----
    b -= NT_TILES * 256;
    const int mt = b >> 8;
    const int rem = b & 255;
    const int kt = rem >> 1, half = rem & 1;
    const int r = half * 128 + (tid >> 1);
    const int s0 = (tid & 1) * 2;
    const int k0 = kt * 32 + s0 * 8;

    const float4* p = (const float4*)(x + (size_t)(mt * 256 + r) * K_DIM + k0);
    float4 f0 = p[0], f1 = p[1], f2 = p[2], f3 = p[3];
    short8 h0, h1;
    h0[0]=f2bf(f0.x); h0[1]=f2bf(f0.y); h0[2]=f2bf(f0.z); h0[3]=f2bf(f0.w);
    h0[4]=f2bf(f1.x); h0[5]=f2bf(f1.y); h0[6]=f2bf(f1.z); h0[7]=f2bf(f1.w);
    h1[0]=f2bf(f2.x); h1[1]=f2bf(f2.y); h1[2]=f2bf(f2.z); h1[3]=f2bf(f2.w);
    h1[4]=f2bf(f3.x); h1[5]=f2bf(f3.y); h1[6]=f2bf(f3.z); h1[7]=f2bf(f3.w);

    const int w = (r >> 1) & 3;
    short* slab = xh + ((size_t)mt * K_TILES + kt) * SLAB;
    *(short8*)&slab[r * 32 + ((s0    ) ^ w) * 8] = h0;
    *(short8*)&slab[r * 32 + ((s0 + 1) ^ w) * 8] = h1;
  }
}

// ============ GEMM: r6 VERBATIM (proven 690 us / 1.07 PF) ============
__global__ __launch_bounds__(512)
void gemm8(const short* __restrict__ xh, const short* __restrict__ wq,
           const void* __restrict__ sv, const void* __restrict__ bv,
           float* __restrict__ C) {
  __shared__ __align__(16) short lds[4 * 2 * SLAB];   // 128 KiB: 4 bufs x (A,B)

  const bool s_is_f32 = sniff_s_is_f32(sv);   // bias dtype tracks scales

  const int tid  = threadIdx.x;
  const int lane = tid & 63;
  const int wid  = tid >> 6;                  // 8 waves
  const int wm = wid >> 2, wn = wid & 3;      // 2x4 -> 128x64 out per wave
  const int lr = lane & 15, lk = lane >> 4;

  // nt-major dispatch (r6-verified: FETCH 1.5G->0.55G)
  const int bid = blockIdx.x;
  const int xcd = bid & 7;
  const int seq = bid >> 3;                   // [0,172)
  const int nt  = seq >> 2;                   // [0,43)
  const int mt  = xcd * 4 + (seq & 3);        // [0,32)

  const short* Aslab = xh + (size_t)mt * K_TILES * SLAB;
  const short* Bslab = wq + (size_t)nt * K_TILES * SLAB;

  // fragment LDS offsets (r4/r6-verified, 0 conflicts)
  const int swz8 = (lk ^ ((lr >> 1) & 3)) << 3;
  int aoff[8], boff[4];
  #pragma unroll
  for (int mi = 0; mi < 8; ++mi) aoff[mi] = (wm * 128 + mi * 16 + lr) * 32 + swz8;
  #pragma unroll
  for (int ni = 0; ni < 4; ++ni) boff[ni] = (wn * 64 + ni * 16 + lr) * 32 + swz8;

  floatx4 acc[8][4];
  #pragma unroll
  for (int i = 0; i < 8; ++i)
    #pragma unroll
    for (int j = 0; j < 4; ++j)
      acc[i][j] = (floatx4){0.f, 0.f, 0.f, 0.f};

  short8 fa[8], fb[4], ga[8], gb[4];   // two named frag sets (rule #20)

#define STAGE(t) do {                                                   \
    const short* gA_ = Aslab + (size_t)(t) * SLAB;                      \
    const short* gB_ = Bslab + (size_t)(t) * SLAB;                      \
    short* lA_ = &lds[((t) & 3) * (2 * SLAB)];                          \
    short* lB_ = lA_ + SLAB;                                            \
    gload_lds16(gA_ + tid * 8,        lA_ + tid * 8);                   \
    gload_lds16(gA_ + 4096 + tid * 8, lA_ + 4096 + tid * 8);            \
    gload_lds16(gB_ + tid * 8,        lB_ + tid * 8);                   \
    gload_lds16(gB_ + 4096 + tid * 8, lB_ + 4096 + tid * 8);            \
  } while (0)

#define LOADF(da, db, t) do {                                           \
    const short* lA_ = &lds[((t) & 3) * (2 * SLAB)];                    \
    const short* lB_ = lA_ + SLAB;                                      \
    _Pragma("unroll")                                                   \
    for (int mi = 0; mi < 8; ++mi) da[mi] = *(const short8*)&lA_[aoff[mi]]; \
    _Pragma("unroll")                                                   \
    for (int ni = 0; ni < 4; ++ni) db[ni] = *(const short8*)&lB_[boff[ni]]; \
  } while (0)

#define DOMFMA(sa, sb) do {                                             \
    __builtin_amdgcn_s_setprio(1);                                      \
    _Pragma("unroll")                                                   \
    for (int mi = 0; mi < 8; ++mi)                                      \
      _Pragma("unroll")                                                 \
      for (int ni = 0; ni < 4; ++ni)                                    \
        acc[mi][ni] = __builtin_amdgcn_mfma_f32_16x16x32_bf16(          \
            sa[mi], sb[ni], acc[mi][ni], 0, 0, 0);                      \
    __builtin_amdgcn_s_setprio(0);                                      \
  } while (0)

#define FENCE asm volatile("" ::: "memory")
#define VMCNT(n) asm volatile("s_waitcnt vmcnt(" #n ")" ::: "memory")
#define BARRIER do { FENCE; __builtin_amdgcn_s_barrier(); FENCE; } while (0)

  // prologue: stage 3 tiles (12 loads/wave outstanding); publish+read tile 0
  STAGE(0); STAGE(1); STAGE(2);
  VMCNT(8);                    // own tile-0 loads retired
  BARRIER;                     // tile 0 published to all waves
  LOADF(fa, fb, 0);

  // Steady state, 2 tiles per loop iter, ONE barrier per tile (r6-proven
  // publish-then-read order).
  for (int kt = 0; kt < 124; kt += 2) {
    VMCNT(4);
    BARRIER;
    STAGE(kt + 3);
    LOADF(ga, gb, kt + 1);
    DOMFMA(fa, fb);            // tile kt
    VMCNT(4);
    BARRIER;
    STAGE(kt + 4);
    LOADF(fa, fb, kt + 2);
    DOMFMA(ga, gb);            // tile kt+1
  }

  // tail: staged through 126; fa holds tile 124.
  VMCNT(4);                    // retire 125
  BARRIER;
  STAGE(127);
  LOADF(ga, gb, 125);
  DOMFMA(fa, fb);              // 124
  VMCNT(4);                    // retire 126
  BARRIER;
  LOADF(fa, fb, 126);
  DOMFMA(ga, gb);              // 125
  VMCNT(0);                    // retire 127
  BARRIER;
  LOADF(ga, gb, 127);
  DOMFMA(fa, fb);              // 126
  DOMFMA(ga, gb);              // 127

#undef STAGE
#undef LOADF
#undef DOMFMA
#undef FENCE
#undef VMCNT
#undef BARRIER

  // epilogue: C/D layout col = lane&15, row = (lane>>4)*4 + reg (verified)
  #pragma unroll
  for (int ni = 0; ni < 4; ++ni) {
    const int col = nt * 256 + wn * 64 + ni * 16 + lr;
    const float bvf = load_sc(bv, (size_t)col, s_is_f32);
    #pragma unroll
    for (int mi = 0; mi < 8; ++mi) {
      const int rbase = mt * 256 + wm * 128 + mi * 16 + lk * 4;
      #pragma unroll
      for (int rr = 0; rr < 4; ++rr)
        C[(size_t)(rbase + rr) * N_DIM + col] = acc[mi][ni][rr] + bvf;
    }
  }
}

// ============ fallback: round-2-verified fully fused kernel ============
__global__ __launch_bounds__(256)
void gemm_fused(const float* __restrict__ x, const void* __restrict__ qv,
                const void* __restrict__ sv, const void* __restrict__ bv,
                float* __restrict__ C) {
  __shared__ __align__(16) short As[128 * 64];
  __shared__ __align__(16) short Bs[128 * 64];

  const bool q_is_i32 = sniff_q_is_i32(qv);
  const bool s_is_f32 = sniff_s_is_f32(sv);

  const int tid  = threadIdx.x;
  const int lane = tid & 63;
  const int wid  = tid >> 6;
  const int wm = wid >> 1, wn = wid & 1;
  const int lr = lane & 15, lk = lane >> 4;

  const int nwg = gridDim.x;
  const int cpx = nwg >> 3;
  const int bid = blockIdx.x;
  const int swz = (bid & 7) * cpx + (bid >> 3);
  const int per_g = 4 * 86;
  const int g = swz / per_g;
  const int r = swz - g * per_g;
  const int mt = (g << 2) + (r & 3);
  const int nt = r >> 2;

  const int row0 = mt * 128;
  const int col0 = nt * 128;

  floatx4 acc[4][4];
  #pragma unroll
  for (int i = 0; i < 4; ++i)
    #pragma unroll
    for (int j = 0; j < 4; ++j)
      acc[i][j] = (floatx4){0.f, 0.f, 0.f, 0.f};

  for (int kt = 0; kt < K_DIM / 64; ++kt) {
    const int k0 = kt * 64;
    #pragma unroll
    for (int i = 0; i < 4; ++i) {
      const int cid = i * 256 + tid;
      const int arow = cid >> 3, ac = (cid & 7) << 3;
      const float4* p = (const float4*)(x + (size_t)(row0 + arow) * K_DIM + k0 + ac);
      float4 a = p[0], b = p[1];
      short8 h;
      h[0]=f2bf(a.x); h[1]=f2bf(a.y); h[2]=f2bf(a.z); h[3]=f2bf(a.w);
      h[4]=f2bf(b.x); h[5]=f2bf(b.y); h[6]=f2bf(b.z); h[7]=f2bf(b.w);
      *(short8*)&As[arow * 64 + ac] = h;
    }
    #pragma unroll
    for (int i = 0; i < 2; ++i) {
      const int cid = i * 256 + tid;
      const int brow = cid >> 2, bc = (cid & 3) << 4;
      const float s = load_sc(sv, (size_t)(col0 + brow) * 64 + kt, s_is_f32);
      int codes[16];
      if (q_is_i32) {
        const int* qq = (const int*)qv + (size_t)(col0 + brow) * K_DIM + k0 + bc;
        #pragma unroll
        for (int j = 0; j < 4; ++j) {
          int4 t = ((const int4*)qq)[j];
          codes[j*4+0]=t.x; codes[j*4+1]=t.y; codes[j*4+2]=t.z; codes[j*4+3]=t.w;
        }
      } else {
        union { int4 v; int8_t c[16]; } u;
        u.v = *(const int4*)((const int8_t*)qv + (size_t)(col0 + brow) * K_DIM + k0 + bc);
        #pragma unroll
        for (int j = 0; j < 16; ++j) codes[j] = (int)u.c[j];
      }
      short8 h0, h1;
      #pragma unroll
      for (int j = 0; j < 8; ++j) h0[j] = f2bf((float)codes[j] * s);
      #pragma unroll
      for (int j = 0; j < 8; ++j) h1[j] = f2bf((float)codes[8 + j] * s);
      *(short8*)&Bs[brow * 64 + bc]     = h0;
      *(short8*)&Bs[brow * 64 + bc + 8] = h1;
    }
    __syncthreads();
    #pragma unroll
    for (int ks = 0; ks < 2; ++ks) {
      short8 a[4], b[4];
      #pragma unroll
      for (int mi = 0; mi < 4; ++mi)
        a[mi] = *(const short8*)&As[(wm * 64 + mi * 16 + lr) * 64 + ks * 32 + lk * 8];
      #pragma unroll
      for (int ni = 0; ni < 4; ++ni)
        b[ni] = *(const short8*)&Bs[(wn * 64 + ni * 16 + lr) * 64 + ks * 32 + lk * 8];
      #pragma unroll
      for (int mi = 0; mi < 4; ++mi)
        #pragma unroll
        for (int ni = 0; ni < 4; ++ni)
          acc[mi][ni] = __builtin_amdgcn_mfma_f32_16x16x32_bf16(
              a[mi], b[ni], acc[mi][ni], 0, 0, 0);
    }
    __syncthreads();
  }

  #pragma unroll
  for (int ni = 0; ni < 4; ++ni) {
    const int col = col0 + wn * 64 + ni * 16 + lr;
    const float bvf = load_sc(bv, (size_t)col, s_is_f32);
    #pragma unroll
    for (int mi = 0; mi < 4; ++mi) {
      const int rbase = row0 + wm * 64 + mi * 16 + lk * 4;
      #pragma unroll
      for (int rr = 0; rr < 4; ++rr)
        C[(size_t)(rbase + rr) * N_DIM + col] = acc[mi][ni][rr] + bvf;
    }
  }
}

extern "C" void kernel_launch(void* const* d_in, const int* in_sizes, int n_in,
                              void* d_out, int out_size, void* d_ws, size_t ws_size,
                              hipStream_t stream) {
  const float* x  = (const float*)d_in[0];
  const void*  q  = (const void*)d_in[1];
  const void*  sc = (const void*)d_in[2];
  const void*  bs = (const void*)d_in[3];
  float* y = (float*)d_out;
  (void)in_sizes; (void)n_in; (void)out_size;

  const size_t xh_bytes = (size_t)M_DIM * K_DIM * 2;   // 64 MiB
  const size_t wq_bytes = (size_t)N_DIM * K_DIM * 2;   // ~86 MiB

  if (ws_size >= xh_bytes + wq_bytes) {   // confirmed available (r3-r7)
    short* xh = (short*)d_ws;
    short* wq = (short*)((char*)d_ws + xh_bytes);
    prep_fused<<<NT_TILES * 256 + MT_TILES * 256, dim3(256), 0, stream>>>(
        x, q, sc, xh, wq);
    gemm8<<<MT_TILES * NT_TILES, dim3(512), 0, stream>>>(xh, wq, sc, bs, y);
  } else {
    gemm_fused<<<(M_DIM / 128) * (N_DIM / 128), dim3(256), 0, stream>>>(x, q, sc, bs, y);
  }
}